// Round 3
// baseline (377.079 us; speedup 1.0000x reference)
//
#include <hip/hip_runtime.h>
#include <hip/hip_bf16.h>

typedef __attribute__((ext_vector_type(8))) short short8;
typedef __attribute__((ext_vector_type(4))) float f32x4;

#define BM 128
#define BN 128
#define BK 64
#define KDIM 7168
#define NDIM 18432
#define SN 56            // KDIM/128 scale cols
#define NTK 112          // KDIM/BK

static __device__ __forceinline__ short bfb(float f) {
    __hip_bfloat16 h = __float2bfloat16(f);
    return __builtin_bit_cast(short, h);
}

extern "C" __global__ void __launch_bounds__(256, 2)
fp8lin_gemm(const float* __restrict__ A,   // [M][K]
            const float* __restrict__ W,   // [N][K]
            const float* __restrict__ S,   // [N/128][K/128]
            float* __restrict__ C,         // [M][N]
            int M)
{
    const int ntile_m = M / BM;            // 4
    const int ntile_n = NDIM / BN;         // 144
    const int nwg = ntile_m * ntile_n;     // 576 (multiple of 8)

    // chunked XCD swizzle: consecutive logical ids land on same XCD;
    // logical order = n-tile major, m-tile minor so the 4 blocks sharing a
    // W panel are adjacent (same XCD -> W fetched ~once into its L2).
    int orig = (int)blockIdx.x;
    int q = nwg >> 3;
    int lid = (orig & 7) * q + (orig >> 3);

    const int tm = lid % ntile_m;
    const int tn = lid / ntile_m;
    const int m0 = tm * BM;
    const int n0 = tn * BN;

    const int tid  = threadIdx.x;
    const int lane = tid & 63;
    const int wid  = tid >> 6;      // 4 waves: 2 (M) x 2 (N)
    const int wm   = wid >> 1;
    const int wn   = wid & 1;

    __shared__ char lds[2][2][BM * BK * 2];   // [dbuf][A/B], bf16 tiles, 64 KiB

    // ---- staging geometry: chunk ch = c*256 + tid; row = ch>>3, kchunk = ch&7
    int st_r[4], st_kc[4], st_byte[4];
#pragma unroll
    for (int c = 0; c < 4; ++c) {
        int ch = c * 256 + tid;
        int r  = ch >> 3;
        int kc = ch & 7;
        st_r[c]  = r;
        st_kc[c] = kc;
        // XOR swizzle: spread the 8 16B k-chunks of a row across banks
        st_byte[c] = r * (BK * 2) + (((kc) << 4) ^ ((r & 7) << 4));
    }

    const float* Abase = A + (size_t)m0 * KDIM;
    const float* Wbase = W + (size_t)n0 * KDIM;

    f32x4 ra[4][2], rb[4][2];

    auto LOADS = [&](int kt) {
        const float* Ak = Abase + kt * BK;
        const float* Wk = Wbase + kt * BK;
#pragma unroll
        for (int c = 0; c < 4; ++c) {
            const float* pa = Ak + (size_t)st_r[c] * KDIM + st_kc[c] * 8;
            ra[c][0] = *(const f32x4*)pa;
            ra[c][1] = *(const f32x4*)(pa + 4);
            const float* pw = Wk + (size_t)st_r[c] * KDIM + st_kc[c] * 8;
            rb[c][0] = *(const f32x4*)pw;
            rb[c][1] = *(const f32x4*)(pw + 4);
        }
    };

    auto WRITES = [&](int buf, float s) {
#pragma unroll
        for (int c = 0; c < 4; ++c) {
            short8 va, vb;
#pragma unroll
            for (int j = 0; j < 4; ++j) {
                va[j]     = bfb(ra[c][0][j]);
                va[j + 4] = bfb(ra[c][1][j]);
                vb[j]     = bfb(rb[c][0][j] * s);
                vb[j + 4] = bfb(rb[c][1][j] * s);
            }
            *(short8*)(&lds[buf][0][st_byte[c]]) = va;
            *(short8*)(&lds[buf][1][st_byte[c]]) = vb;
        }
    };

    f32x4 acc[4][4];
#pragma unroll
    for (int i = 0; i < 4; ++i)
#pragma unroll
        for (int j = 0; j < 4; ++j)
            acc[i][j] = f32x4{0.f, 0.f, 0.f, 0.f};

    const int l15 = lane & 15;
    const int lq  = lane >> 4;

    auto COMPUTE = [&](int buf) {
        const char* la = lds[buf][0];
        const char* lb = lds[buf][1];
#pragma unroll
        for (int kk = 0; kk < 2; ++kk) {
            int kc = kk * 4 + lq;           // 16B chunk index along K
            short8 af[4], bq[4];
#pragma unroll
            for (int i = 0; i < 4; ++i) {
                int r = wm * 64 + i * 16 + l15;
                af[i] = *(const short8*)(la + r * (BK * 2) + ((kc << 4) ^ ((r & 7) << 4)));
            }
#pragma unroll
            for (int j = 0; j < 4; ++j) {
                int r = wn * 64 + j * 16 + l15;
                bq[j] = *(const short8*)(lb + r * (BK * 2) + ((kc << 4) ^ ((r & 7) << 4)));
            }
#pragma unroll
            for (int i = 0; i < 4; ++i)
#pragma unroll
                for (int j = 0; j < 4; ++j)
                    acc[i][j] = __builtin_amdgcn_mfma_f32_16x16x32_bf16(af[i], bq[j], acc[i][j], 0, 0, 0);
        }
    };

    // scale: one scalar per (n-tile, K-step) since BN==128 == scale block
    const float* Srow = S + (size_t)tn * SN;

    LOADS(0);
    WRITES(0, Srow[0]);
    LOADS(1);                 // issue early; consumed after first COMPUTE
    __syncthreads();

    int cur = 0;
    for (int kt = 0; kt < NTK; ++kt) {
        COMPUTE(cur);
        if (kt + 1 < NTK) {
            WRITES(cur ^ 1, Srow[(kt + 1) >> 1]);
            if (kt + 2 < NTK) LOADS(kt + 2);
        }
        __syncthreads();
        cur ^= 1;
    }

    // ---- epilogue: C/D layout col=lane&15, row=(lane>>4)*4+r
    float* Cb = C + (size_t)(m0 + wm * 64) * NDIM + (n0 + wn * 64);
    const int crow = lq * 4;
#pragma unroll
    for (int i = 0; i < 4; ++i) {
#pragma unroll
        for (int r = 0; r < 4; ++r) {
            float* Cr = Cb + (size_t)(i * 16 + crow + r) * NDIM + l15;
#pragma unroll
            for (int j = 0; j < 4; ++j)
                Cr[j * 16] = acc[i][j][r];
        }
    }
}

extern "C" void kernel_launch(void* const* d_in, const int* in_sizes, int n_in,
                              void* d_out, int out_size, void* d_ws, size_t ws_size,
                              hipStream_t stream) {
    const float* inp = (const float*)d_in[0];   // [1,512,7168] fp32
    const float* w   = (const float*)d_in[1];   // [18432,7168] fp32
    const float* s   = (const float*)d_in[2];   // [144,56] fp32
    float* out       = (float*)d_out;           // [1,512,18432] fp32

    int M = in_sizes[0] / KDIM;                 // 512
    int grid = (M / BM) * (NDIM / BN);          // 576
    hipLaunchKernelGGL(fp8lin_gemm, dim3(grid), dim3(256), 0, stream,
                       inp, w, s, out, M);
}

// Round 4
// 285.956 us; speedup vs baseline: 1.3187x; 1.3187x over previous
//
#include <hip/hip_runtime.h>
#include <hip/hip_bf16.h>

typedef __attribute__((ext_vector_type(8))) short short8;
typedef __attribute__((ext_vector_type(4))) float f32x4;

#define BM 128
#define BN 128
#define BK 64
#define KDIM 7168
#define NDIM 18432
#define SN 56            // KDIM/128 scale cols
#define NTK 112          // KDIM/BK

static __device__ __forceinline__ short bfb(float f) {
    __hip_bfloat16 h = __float2bfloat16(f);
    return __builtin_bit_cast(short, h);
}

// ---- pre-kernel: A fp32 -> bf16 row-major in d_ws ----
extern "C" __global__ void __launch_bounds__(256)
a_to_bf16(const float* __restrict__ A, __hip_bfloat16* __restrict__ Ab, int n8) {
    int i = blockIdx.x * blockDim.x + threadIdx.x;
    if (i >= n8) return;
    const f32x4* p = (const f32x4*)(A + (size_t)i * 8);
    f32x4 v0 = p[0], v1 = p[1];
    short8 o;
#pragma unroll
    for (int j = 0; j < 4; ++j) { o[j] = bfb(v0[j]); o[j + 4] = bfb(v1[j]); }
    *(short8*)(Ab + (size_t)i * 8) = o;
}

// AMODE 1: A pre-converted bf16 in ws.  AMODE 0: A fp32 direct (fallback).
template <int AMODE>
__global__ void __launch_bounds__(512, 4)
fp8lin_gemm(const float* __restrict__ A,              // [M][K] fp32
            const __hip_bfloat16* __restrict__ Ab,    // [M][K] bf16 (ws)
            const float* __restrict__ W,              // [N][K] fp32
            const float* __restrict__ S,              // [N/128][K/128]
            float* __restrict__ C,                    // [M][N]
            int M)
{
    const int ntile_m = M / BM;            // 4
    const int ntile_n = NDIM / BN;         // 144
    const int nwg = ntile_m * ntile_n;     // 576 (multiple of 8)

    // chunked XCD swizzle; n-major/m-minor so the 4 blocks sharing a W panel
    // are adjacent -> same XCD L2.
    int orig = (int)blockIdx.x;
    int q = nwg >> 3;
    int lid = (orig & 7) * q + (orig >> 3);

    const int tm = lid % ntile_m;
    const int tn = lid / ntile_m;
    const int m0 = tm * BM;
    const int n0 = tn * BN;

    const int tid  = threadIdx.x;
    const int lane = tid & 63;
    const int wid  = tid >> 6;      // 8 waves: 2(M) x 4(N)
    const int wm   = wid >> 2;
    const int wn   = wid & 3;

    __shared__ char lds[2][2][BM * BK * 2];   // [dbuf][A=0/W=1] bf16, 64 KiB

    // staging geometry: 1024 16B-bf16 units per operand; unit u = c*512+tid
    // row = u>>3, kc8 = u&7 (8 bf16 elems each). XOR-swizzled LDS byte.
    int st_row[2], st_kc[2], st_byte[2];
#pragma unroll
    for (int c = 0; c < 2; ++c) {
        int u = c * 512 + tid;
        int r  = u >> 3;
        int kc = u & 7;
        st_row[c]  = r;
        st_kc[c]   = kc;
        st_byte[c] = r * (BK * 2) + ((kc << 4) ^ ((r & 7) << 4));
    }

    const float*          Afp = A  + (size_t)m0 * KDIM;
    const __hip_bfloat16* Abf = Ab + (size_t)m0 * KDIM;
    const float*          Wb  = W  + (size_t)n0 * KDIM;

    f32x4 rw[2][2];        // W fp32 staging
    f32x4 raf[2][2];       // A fp32 staging (AMODE 0)
    short8 ra8[2];         // A bf16 staging (AMODE 1)

    auto LOADS = [&](int kt) {
        const int kof = kt * BK;
#pragma unroll
        for (int c = 0; c < 2; ++c) {
            const float* pw = Wb + (size_t)st_row[c] * KDIM + kof + st_kc[c] * 8;
            rw[c][0] = *(const f32x4*)pw;
            rw[c][1] = *(const f32x4*)(pw + 4);
            if (AMODE) {
                ra8[c] = *(const short8*)(Abf + (size_t)st_row[c] * KDIM + kof + st_kc[c] * 8);
            } else {
                const float* pa = Afp + (size_t)st_row[c] * KDIM + kof + st_kc[c] * 8;
                raf[c][0] = *(const f32x4*)pa;
                raf[c][1] = *(const f32x4*)(pa + 4);
            }
        }
    };

    auto WRITES = [&](int buf, float s) {
#pragma unroll
        for (int c = 0; c < 2; ++c) {
            short8 vw;
#pragma unroll
            for (int j = 0; j < 4; ++j) {
                vw[j]     = bfb(rw[c][0][j] * s);
                vw[j + 4] = bfb(rw[c][1][j] * s);
            }
            *(short8*)(&lds[buf][1][st_byte[c]]) = vw;
            if (AMODE) {
                *(short8*)(&lds[buf][0][st_byte[c]]) = ra8[c];
            } else {
                short8 va;
#pragma unroll
                for (int j = 0; j < 4; ++j) {
                    va[j]     = bfb(raf[c][0][j]);
                    va[j + 4] = bfb(raf[c][1][j]);
                }
                *(short8*)(&lds[buf][0][st_byte[c]]) = va;
            }
        }
    };

    f32x4 acc[4][2];
#pragma unroll
    for (int i = 0; i < 4; ++i)
#pragma unroll
        for (int j = 0; j < 2; ++j)
            acc[i][j] = f32x4{0.f, 0.f, 0.f, 0.f};

    const int l15 = lane & 15;
    const int lq  = lane >> 4;

    auto COMPUTE = [&](int buf) {
        const char* la = lds[buf][0];
        const char* lb = lds[buf][1];
#pragma unroll
        for (int kk = 0; kk < 2; ++kk) {
            int kc = kk * 4 + lq;
            short8 af[4], bq[2];
#pragma unroll
            for (int i = 0; i < 4; ++i) {
                int r = wm * 64 + i * 16 + l15;
                af[i] = *(const short8*)(la + r * (BK * 2) + ((kc << 4) ^ ((r & 7) << 4)));
            }
#pragma unroll
            for (int j = 0; j < 2; ++j) {
                int r = wn * 32 + j * 16 + l15;
                bq[j] = *(const short8*)(lb + r * (BK * 2) + ((kc << 4) ^ ((r & 7) << 4)));
            }
            __builtin_amdgcn_s_setprio(1);
#pragma unroll
            for (int i = 0; i < 4; ++i)
#pragma unroll
                for (int j = 0; j < 2; ++j)
                    acc[i][j] = __builtin_amdgcn_mfma_f32_16x16x32_bf16(af[i], bq[j], acc[i][j], 0, 0, 0);
            __builtin_amdgcn_s_setprio(0);
        }
    };

    const float* Srow = S + (size_t)tn * SN;

    LOADS(0);
    WRITES(0, Srow[0]);
    LOADS(1);
    __syncthreads();

    int cur = 0;
    for (int kt = 0; kt < NTK; ++kt) {
        COMPUTE(cur);
        if (kt + 1 < NTK) {
            WRITES(cur ^ 1, Srow[(kt + 1) >> 1]);
            if (kt + 2 < NTK) LOADS(kt + 2);
        }
        __syncthreads();
        cur ^= 1;
    }

    // epilogue: C/D layout col=lane&15, row=(lane>>4)*4+r
    float* Cb = C + (size_t)(m0 + wm * 64) * NDIM + (n0 + wn * 32);
    const int crow = lq * 4;
#pragma unroll
    for (int i = 0; i < 4; ++i) {
#pragma unroll
        for (int r = 0; r < 4; ++r) {
            float* Cr = Cb + (size_t)(i * 16 + crow + r) * NDIM + l15;
#pragma unroll
            for (int j = 0; j < 2; ++j)
                Cr[j * 16] = acc[i][j][r];
        }
    }
}

extern "C" void kernel_launch(void* const* d_in, const int* in_sizes, int n_in,
                              void* d_out, int out_size, void* d_ws, size_t ws_size,
                              hipStream_t stream) {
    const float* inp = (const float*)d_in[0];   // [1,512,7168] fp32
    const float* w   = (const float*)d_in[1];   // [18432,7168] fp32
    const float* s   = (const float*)d_in[2];   // [144,56] fp32
    float* out       = (float*)d_out;           // [1,512,18432] fp32

    int M = in_sizes[0] / KDIM;                 // 512
    int grid = (M / BM) * (NDIM / BN);          // 576
    size_t need = (size_t)M * KDIM * sizeof(__hip_bfloat16);

    if (ws_size >= need) {
        __hip_bfloat16* ab = (__hip_bfloat16*)d_ws;
        int n8 = M * KDIM / 8;
        hipLaunchKernelGGL(a_to_bf16, dim3((n8 + 255) / 256), dim3(256), 0, stream,
                           inp, ab, n8);
        hipLaunchKernelGGL((fp8lin_gemm<1>), dim3(grid), dim3(512), 0, stream,
                           inp, ab, w, s, out, M);
    } else {
        hipLaunchKernelGGL((fp8lin_gemm<0>), dim3(grid), dim3(512), 0, stream,
                           inp, (const __hip_bfloat16*)nullptr, w, s, out, M);
    }
}